// Round 1
// 1108.776 us; speedup vs baseline: 1.0778x; 1.0778x over previous
//
#include <hip/hip_runtime.h>
#include <stdint.h>

#define NH 4
#define HD 64
#define DM 256
#define BB 16
#define PLEN 512
#define GLEN 16384
#define ML 16
#define NCH_MAX 32

typedef __attribute__((ext_vector_type(8))) short bf16x8;
typedef __attribute__((ext_vector_type(4))) short s16x4;
typedef __attribute__((ext_vector_type(4))) float f32x4;
struct fl4 { float x, y, z, w; };

#define MFMA16(a, b, c) __builtin_amdgcn_mfma_f32_16x16x32_bf16((a), (b), (c), 0, 0, 0)

__device__ __forceinline__ float bf2f(short x) {
  union { unsigned u; float f; } v;
  v.u = ((unsigned)(unsigned short)x) << 16;
  return v.f;
}
__device__ __forceinline__ short f2bf(float x) {
  union { float f; unsigned u; } v;
  v.f = x;
  unsigned u = v.u;
  u += 0x7fffu + ((u >> 16) & 1u);  // RNE
  return (short)(u >> 16);
}

// ---------------- dtype detection: fp32-as-bf16 even shorts are wild ----------------
__global__ void detect_dtype(const short* __restrict__ pattern, int* __restrict__ flag) {
  int t = threadIdx.x;
  int bad = 0;
  for (int i = t; i < 4096; i += 256) {
    float v = bf2f(pattern[2 * i]);
    if (!(fabsf(v) < 1e10f)) bad++;  // catches huge AND NaN
  }
  __shared__ int cnt;
  if (t == 0) cnt = 0;
  __syncthreads();
  if (bad) atomicAdd(&cnt, bad);
  __syncthreads();
  if (t == 0) flag[0] = (cnt > 8) ? 1 : 0;  // 1 = inputs are float32
}

// ---------------- fused: dtype-convert + meanpool partial sums + K/V projection ----------------
// One block = 64 rows of X. Computes K rows (row-major) and V (transposed) for those rows,
// plus per-block column sums (for graph mean-pool init) when partials != nullptr.
// X tile staged in LDS with chunk^(row&7) XOR swizzle (16B granules) to kill the
// stride-512B 32-way bank conflict on A-fragment ds_read_b128.
// 8 waves: waves 0-3 -> K cols wave*64.., waves 4-7 -> V cols (wave-4)*64..
// Exactly ONE barrier per block; cross-block overlap (2 blocks/CU) pipelines staging.
__global__ __launch_bounds__(512, 4) void proj_kv_fused(
    const void* __restrict__ Xraw, const short* __restrict__ WkT,
    const short* __restrict__ WvT, short* __restrict__ Kout,
    short* __restrict__ Vt, int L, float* __restrict__ partials,
    const int* __restrict__ flag) {
  __shared__ __align__(16) short Xs[64 * DM];  // 32 KB, swizzled
  __shared__ float scr[16 * DM];               // 16 KB, col-sum scratch
  const int isf = flag[0];
  const int t = threadIdx.x;
  const int row0 = blockIdx.x * 64;
  const int tc2 = t & 31, tr2 = t >> 5;  // col-chunk (8 elems), row-within-16
  float s[8];
#pragma unroll
  for (int j = 0; j < 8; j++) s[j] = 0.f;
  if (isf) {
    const float* xf = (const float*)Xraw + (size_t)row0 * DM + tc2 * 8;
#pragma unroll
    for (int it = 0; it < 4; it++) {
      int row = it * 16 + tr2;
      fl4 v0 = *(const fl4*)(xf + (size_t)row * DM);
      fl4 v1 = *(const fl4*)(xf + (size_t)row * DM + 4);
      s[0] += v0.x; s[1] += v0.y; s[2] += v0.z; s[3] += v0.w;
      s[4] += v1.x; s[5] += v1.y; s[6] += v1.z; s[7] += v1.w;
      bf16x8 o;
      o[0] = f2bf(v0.x); o[1] = f2bf(v0.y); o[2] = f2bf(v0.z); o[3] = f2bf(v0.w);
      o[4] = f2bf(v1.x); o[5] = f2bf(v1.y); o[6] = f2bf(v1.z); o[7] = f2bf(v1.w);
      *(bf16x8*)(Xs + row * DM + (tc2 ^ (row & 7)) * 8) = o;
    }
  } else {
    const short* xb = (const short*)Xraw + (size_t)row0 * DM + tc2 * 8;
#pragma unroll
    for (int it = 0; it < 4; it++) {
      int row = it * 16 + tr2;
      bf16x8 v = *(const bf16x8*)(xb + (size_t)row * DM);
#pragma unroll
      for (int j = 0; j < 8; j++) s[j] += bf2f(v[j]);
      *(bf16x8*)(Xs + row * DM + (tc2 ^ (row & 7)) * 8) = v;
    }
  }
  if (partials) {
#pragma unroll
    for (int j = 0; j < 8; j++) scr[tr2 * DM + tc2 * 8 + j] = s[j];
  }
  __syncthreads();  // Xs (and scr) visible — the only barrier
  if (partials && t < DM) {
    float a = 0.f;
#pragma unroll
    for (int i = 0; i < 16; i++) a += scr[i * DM + t];
    partials[(size_t)blockIdx.x * DM + t] = a;
  }
  const int wave = t >> 6, lane = t & 63, quad = lane >> 4, l16 = lane & 15;
  const int kv = wave >> 2;
  const int wc = (wave & 3) * 64;
  const short* WT = kv ? WvT : WkT;  // [n][k] bf16, L2-resident (128 KB each)
  f32x4 z = {0.f, 0.f, 0.f, 0.f};
  f32x4 acc[4][4];
#pragma unroll
  for (int i = 0; i < 4; i++)
#pragma unroll
    for (int j = 0; j < 4; j++) acc[i][j] = z;
#pragma unroll
  for (int kk = 0; kk < 8; kk++) {
    bf16x8 a[4], bw[4];
#pragma unroll
    for (int rt = 0; rt < 4; rt++) {
      int rw = rt * 16 + l16;
      a[rt] = *(const bf16x8*)(Xs + rw * DM + (((kk * 4 + quad) ^ (rw & 7)) * 8));
    }
#pragma unroll
    for (int ct = 0; ct < 4; ct++)
      bw[ct] = *(const bf16x8*)(WT + (size_t)(wc + ct * 16 + l16) * DM + kk * 32 + quad * 8);
#pragma unroll
    for (int rt = 0; rt < 4; rt++)
#pragma unroll
      for (int ct = 0; ct < 4; ct++)
        acc[rt][ct] = MFMA16(a[rt], bw[ct], acc[rt][ct]);
  }
  if (kv == 0) {
#pragma unroll
    for (int rt = 0; rt < 4; rt++)
#pragma unroll
      for (int ct = 0; ct < 4; ct++) {
        int col = wc + ct * 16 + l16;
#pragma unroll
        for (int r = 0; r < 4; r++)
          Kout[(size_t)(row0 + rt * 16 + quad * 4 + r) * DM + col] = f2bf(acc[rt][ct][r]);
      }
  } else {
    int bb = row0 / L, j0v = row0 % L;
#pragma unroll
    for (int rt = 0; rt < 4; rt++) {
      int j = j0v + rt * 16 + quad * 4;
#pragma unroll
      for (int ct = 0; ct < 4; ct++) {
        int c = wc + ct * 16 + l16;
        s16x4 pv;
#pragma unroll
        for (int r = 0; r < 4; r++) pv[r] = f2bf(acc[rt][ct][r]);
        *(s16x4*)(Vt + ((size_t)bb * DM + c) * L + j) = pv;
      }
    }
  }
}

// ---------------- finalize mean + first q-projection ----------------
// partials are now per-64-row blocks: 16 per (b,m) segment of 1024 rows.
__global__ __launch_bounds__(256) void finalize_q0(
    const float* __restrict__ partials, const void* __restrict__ Wq,
    float* __restrict__ mem, short* __restrict__ hq, const int* __restrict__ flag) {
  int b = blockIdx.x >> 4, m = blockIdx.x & 15;
  int t = threadIdx.x;
  int isf = flag[0];
  int p0 = b * 256 + m * 16;  // first partial-block of this (b,m) segment
  float s = 0.f;
#pragma unroll
  for (int i = 0; i < 16; i++) s += partials[(size_t)(p0 + i) * 256 + t];
  float v = s * (1.0f / 1024.0f);
  __shared__ float memrow[256];
  memrow[t] = bf2f(f2bf(v));  // bf16-rounded copy (matches MFMA path numerics)
  mem[((size_t)b * ML + m) * DM + t] = v;
  __syncthreads();
  float acc = 0.f;
  if (isf) {
    const float* wf = (const float*)Wq;
    for (int k = 0; k < 256; k++)
      acc += memrow[k] * bf2f(f2bf(wf[(size_t)k * 256 + t]));
  } else {
    const short* wsp = (const short*)Wq;
    for (int k = 0; k < 256; k++)
      acc += memrow[k] * bf2f(wsp[(size_t)k * 256 + t]);
  }
  hq[((size_t)b * ML + m) * DM + t] = f2bf(acc);
}

// ---------------- weight transpose (+dtype convert): W[K][256] -> WT[256][K] bf16 ----------------
struct WTArgs {
  const void* src[10];
  short* dst[10];
  int rows[10];
};

__global__ void transpose_w(WTArgs a, const int* __restrict__ flag) {
  int mid = blockIdx.z;
  int K = a.rows[mid];
  int tk = blockIdx.x, tn = blockIdx.y;
  if (tk * 32 >= K) return;  // block-uniform
  int isf = flag[0];
  __shared__ short tile[32][33];
  const short* src = (const short*)a.src[mid];
  const float* srcf = (const float*)a.src[mid];
  short* dst = a.dst[mid];
  int tx = threadIdx.x, ty = threadIdx.y;  // 32 x 8
  for (int i = 0; i < 32; i += 8) {
    size_t idx = (size_t)(tk * 32 + ty + i) * 256 + tn * 32 + tx;
    tile[ty + i][tx] = isf ? f2bf(srcf[idx]) : src[idx];
  }
  __syncthreads();
  for (int i = 0; i < 32; i += 8)
    dst[(size_t)(tn * 32 + ty + i) * K + tk * 32 + tx] = tile[tx][ty + i];
}

// ---------------- bias convert ----------------
__global__ void conv_bias(const void* p_bg, const void* g_bg, short* out,
                          const int* __restrict__ flag) {
  int t = threadIdx.x;
  int isf = flag[0];
  out[t] = isf ? f2bf(((const float*)p_bg)[t]) : ((const short*)p_bg)[t];
  out[256 + t] = isf ? f2bf(((const float*)g_bg)[t]) : ((const short*)g_bg)[t];
}

// ---------------- flash attention partials (one wave = one head) ----------------
__global__ __launch_bounds__(256, 4) void flash_partial(
    const short* __restrict__ hq, const short* __restrict__ Kb,
    const short* __restrict__ Vt, const int* __restrict__ mask,
    float* __restrict__ pm, float* __restrict__ pl, float* __restrict__ pO,
    int L, int NCH) {
  int ch = blockIdx.x, b = blockIdx.y;
  int C = L / NCH;
  int t = threadIdx.x, wave = t >> 6, lane = t & 63, quad = lane >> 4, l16 = lane & 15;
  __shared__ __align__(16) short Plds[4][512];  // per-wave P tile: [q][32 keys]
  short* myP = &Plds[wave][0];
  const short* qbase = hq + ((size_t)b * ML + l16) * DM + wave * HD;
  bf16x8 aq0 = *(const bf16x8*)(qbase + quad * 8);
  bf16x8 aq1 = *(const bf16x8*)(qbase + 32 + quad * 8);
  f32x4 z = {0.f, 0.f, 0.f, 0.f};
  float m_run[4], l_run[4];
  f32x4 O[4];
#pragma unroll
  for (int r = 0; r < 4; r++) { m_run[r] = -1e30f; l_run[r] = 0.f; }
#pragma unroll
  for (int d = 0; d < 4; d++) O[d] = z;
  int j0 = ch * C;
  const float L2E = 1.44269504f;
  for (int jt = 0; jt < C; jt += 32) {
    f32x4 S[2];
#pragma unroll
    for (int tt = 0; tt < 2; tt++) {
      int j = j0 + jt + tt * 16 + l16;
      const short* kb = Kb + ((size_t)b * L + j) * DM + wave * HD;
      bf16x8 b0 = *(const bf16x8*)(kb + quad * 8);
      bf16x8 b1 = *(const bf16x8*)(kb + 32 + quad * 8);
      f32x4 s = MFMA16(aq0, b0, z);
      s = MFMA16(aq1, b1, s);
      int mk = mask[(size_t)b * L + j];
#pragma unroll
      for (int r = 0; r < 4; r++)
        S[tt][r] = mk ? s[r] * 0.125f : -1e30f;
    }
    float p[2][4], alpha[4];
#pragma unroll
    for (int r = 0; r < 4; r++) {
      float v = fmaxf(S[0][r], S[1][r]);
      v = fmaxf(v, __shfl_xor(v, 1, 16));
      v = fmaxf(v, __shfl_xor(v, 2, 16));
      v = fmaxf(v, __shfl_xor(v, 4, 16));
      v = fmaxf(v, __shfl_xor(v, 8, 16));
      float nm = fmaxf(m_run[r], v);
      alpha[r] = exp2f((m_run[r] - nm) * L2E);
      m_run[r] = nm;
      p[0][r] = exp2f((S[0][r] - nm) * L2E);
      p[1][r] = exp2f((S[1][r] - nm) * L2E);
      float ps = p[0][r] + p[1][r];
      ps += __shfl_xor(ps, 1, 16);
      ps += __shfl_xor(ps, 2, 16);
      ps += __shfl_xor(ps, 4, 16);
      ps += __shfl_xor(ps, 8, 16);
      l_run[r] = l_run[r] * alpha[r] + ps;
    }
#pragma unroll
    for (int d = 0; d < 4; d++)
#pragma unroll
      for (int r = 0; r < 4; r++) O[d][r] *= alpha[r];
#pragma unroll
    for (int tt = 0; tt < 2; tt++)
#pragma unroll
      for (int r = 0; r < 4; r++)
        myP[(quad * 4 + r) * 32 + tt * 16 + l16] = f2bf(p[tt][r]);
    __syncthreads();  // P visible (uniform trip count)
    bf16x8 ap = *(const bf16x8*)(myP + l16 * 32 + quad * 8);
#pragma unroll
    for (int d = 0; d < 4; d++) {
      const short* vb = Vt + ((size_t)b * DM + wave * HD + d * 16 + l16) * L + j0 + jt + quad * 8;
      bf16x8 bv = *(const bf16x8*)vb;
      O[d] = MFMA16(ap, bv, O[d]);
    }
    __syncthreads();  // protect P tile
  }
  size_t base = (((size_t)b * NCH + ch) * NH + wave) * ML;
  if (l16 == 0) {
#pragma unroll
    for (int r = 0; r < 4; r++) {
      pm[base + quad * 4 + r] = m_run[r];
      pl[base + quad * 4 + r] = l_run[r];
    }
  }
#pragma unroll
  for (int d = 0; d < 4; d++)
#pragma unroll
    for (int r = 0; r < 4; r++)
      pO[(base + quad * 4 + r) * 64 + d * 16 + l16] = O[d][r];
}

// ---------------- reduce partials + Wo + gate + (next Wq | final out), per batch ----------------
__global__ __launch_bounds__(256, 2) void epilogue(
    const float* __restrict__ pm, const float* __restrict__ pl,
    const float* __restrict__ pO, int NCH,
    float* __restrict__ mem, const short* __restrict__ WoT,
    const short* __restrict__ WgT, const short* __restrict__ bg,
    const short* __restrict__ WqT, short* __restrict__ hq,
    void* __restrict__ outb, const int* __restrict__ flag) {
  int b = blockIdx.x, t = threadIdx.x;
  int isf = flag[0];
  __shared__ float w_lds[NCH_MAX * 64];
  __shared__ float invL[64];
  __shared__ __align__(16) short vec_bf[ML * DM];
  __shared__ __align__(16) short mem_bf[ML * DM];
  __shared__ __align__(16) short attn_bf[ML * DM];
  __shared__ float attn_f[ML * DM];
  __shared__ __align__(16) short memn_bf[ML * DM];

  for (int idx = t; idx < ML * DM; idx += 256)
    mem_bf[idx] = f2bf(mem[(size_t)b * ML * DM + idx]);
  if (t < 64) {  // t = n*16 + i
    size_t base = (size_t)b * NCH * NH * ML + t;
    float M = -1e30f;
    for (int ch = 0; ch < NCH; ch++)
      M = fmaxf(M, pm[base + (size_t)ch * NH * ML]);
    float Ls = 0.f;
    for (int ch = 0; ch < NCH; ch++) {
      float w = exp2f((pm[base + (size_t)ch * NH * ML] - M) * 1.44269504f);
      w_lds[ch * 64 + t] = w;
      Ls += w * pl[base + (size_t)ch * NH * ML];
    }
    invL[t] = 1.0f / Ls;
  }
  __syncthreads();
  {
    int n = t >> 6, d = t & 63;
    for (int i = 0; i < 16; i++) {
      size_t pb = ((size_t)b * NCH * NH * ML + n * ML + i) * 64 + d;
      float o = 0.f;
      for (int ch = 0; ch < NCH; ch++)
        o += w_lds[ch * 64 + n * 16 + i] * pO[pb + (size_t)ch * NH * ML * 64];
      vec_bf[i * DM + n * 64 + d] = f2bf(o * invL[n * 16 + i]);
    }
  }
  __syncthreads();
  int wave = t >> 6, lane = t & 63, quad = lane >> 4, l16 = lane & 15;
  f32x4 z = {0.f, 0.f, 0.f, 0.f};
  f32x4 acc[4];
#pragma unroll
  for (int c = 0; c < 4; c++) acc[c] = z;
#pragma unroll
  for (int kk = 0; kk < 8; kk++) {
    bf16x8 a = *(const bf16x8*)(vec_bf + l16 * DM + kk * 32 + quad * 8);
#pragma unroll
    for (int ct = 0; ct < 4; ct++) {
      const short* wb = WoT + (size_t)(wave * 64 + ct * 16 + l16) * DM + kk * 32 + quad * 8;
      acc[ct] = MFMA16(a, *(const bf16x8*)wb, acc[ct]);
    }
  }
#pragma unroll
  for (int ct = 0; ct < 4; ct++)
#pragma unroll
    for (int r = 0; r < 4; r++) {
      int row = quad * 4 + r, col = wave * 64 + ct * 16 + l16;
      attn_f[row * DM + col] = acc[ct][r];
      attn_bf[row * DM + col] = f2bf(acc[ct][r]);
    }
  __syncthreads();
  f32x4 g[4];
#pragma unroll
  for (int c = 0; c < 4; c++) g[c] = z;
#pragma unroll
  for (int kk = 0; kk < 16; kk++) {
    bf16x8 a = (kk < 8)
        ? *(const bf16x8*)(mem_bf + l16 * DM + kk * 32 + quad * 8)
        : *(const bf16x8*)(attn_bf + l16 * DM + (kk - 8) * 32 + quad * 8);
#pragma unroll
    for (int ct = 0; ct < 4; ct++) {
      const short* wb = WgT + (size_t)(wave * 64 + ct * 16 + l16) * 512 + kk * 32 + quad * 8;
      g[ct] = MFMA16(a, *(const bf16x8*)wb, g[ct]);
    }
  }
#pragma unroll
  for (int ct = 0; ct < 4; ct++)
#pragma unroll
    for (int r = 0; r < 4; r++) {
      int row = quad * 4 + r, col = wave * 64 + ct * 16 + l16;
      float x = g[ct][r] + bf2f(bg[col]);
      float gg = 1.0f / (1.0f + exp2f(-x * 1.44269504f));
      float old = mem[(size_t)b * ML * DM + row * DM + col];
      float mn = gg * old + (1.0f - gg) * attn_f[row * DM + col];
      mem[(size_t)b * ML * DM + row * DM + col] = mn;
      memn_bf[row * DM + col] = f2bf(mn);
      if (outb) {
        size_t oi = (size_t)b * ML * DM + row * DM + col;
        if (isf) ((float*)outb)[oi] = mn;
        else ((short*)outb)[oi] = f2bf(mn);
      }
    }
  __syncthreads();
  if (WqT) {
    f32x4 h[4];
#pragma unroll
    for (int c = 0; c < 4; c++) h[c] = z;
#pragma unroll
    for (int kk = 0; kk < 8; kk++) {
      bf16x8 a = *(const bf16x8*)(memn_bf + l16 * DM + kk * 32 + quad * 8);
#pragma unroll
      for (int ct = 0; ct < 4; ct++) {
        const short* wb = WqT + (size_t)(wave * 64 + ct * 16 + l16) * DM + kk * 32 + quad * 8;
        h[ct] = MFMA16(a, *(const bf16x8*)wb, h[ct]);
      }
    }
#pragma unroll
    for (int ct = 0; ct < 4; ct++)
#pragma unroll
      for (int r = 0; r < 4; r++)
        hq[(size_t)b * ML * DM + (quad * 4 + r) * DM + wave * 64 + ct * 16 + l16] = f2bf(h[ct][r]);
  }
}

// ---------------- launch ----------------
extern "C" void kernel_launch(void* const* d_in, const int* in_sizes, int n_in,
                              void* d_out, int out_size, void* d_ws, size_t ws_size,
                              hipStream_t stream) {
  const void* pattern = d_in[0];
  const void* graph = d_in[1];
  const int* pmask = (const int*)d_in[2];
  const int* gmask = (const int*)d_in[3];

  char* ws = (char*)d_ws;
  size_t off = 0;
  auto alloc = [&](size_t bytes) {
    void* p = ws + off;
    off = (off + bytes + 255) & ~(size_t)255;
    return p;
  };
  int* flag = (int*)alloc(4);
  // WT order: 0 pWqT 1 pWkT 2 pWvT 3 pWoT 4 pWgT 5 gWqT 6 gWkT 7 gWvT 8 gWoT 9 gWgT
  int rows[10] = {256, 256, 256, 256, 512, 256, 256, 256, 256, 512};
  int srcidx[10] = {4, 5, 6, 7, 8, 10, 11, 12, 13, 14};
  short* WT[10];
  for (int i = 0; i < 10; i++) WT[i] = (short*)alloc((size_t)rows[i] * 256 * 2);
  short* bgc = (short*)alloc(512 * 2);  // [p_bg(256), g_bg(256)]
  short* Kp = (short*)alloc((size_t)BB * PLEN * DM * 2);
  short* Vpt = (short*)alloc((size_t)BB * PLEN * DM * 2);
  short* Kg = (short*)alloc((size_t)BB * GLEN * DM * 2);
  short* Vgt = (short*)alloc((size_t)BB * GLEN * DM * 2);
  short* hq = (short*)alloc((size_t)BB * ML * DM * 2);
  float* memf = (float*)alloc((size_t)BB * ML * DM * 4);
  float* pm = (float*)alloc((size_t)BB * NCH_MAX * NH * ML * 4);
  float* pl = (float*)alloc((size_t)BB * NCH_MAX * NH * ML * 4);
  float* pO = (float*)alloc((size_t)BB * NCH_MAX * NH * ML * 64 * 4);
  float* partG = (float*)alloc((size_t)(BB * GLEN / 64) * 256 * 4);  // 4 MB
  if (off > ws_size) return;  // ws too small: output stays zero -> diagnostic signal

  detect_dtype<<<dim3(1), dim3(256), 0, stream>>>((const short*)pattern, flag);

  WTArgs wa;
  for (int i = 0; i < 10; i++) {
    wa.src[i] = d_in[srcidx[i]];
    wa.dst[i] = WT[i];
    wa.rows[i] = rows[i];
  }
  transpose_w<<<dim3(16, 8, 10), dim3(32, 8), 0, stream>>>(wa, flag);
  conv_bias<<<dim3(1), dim3(256), 0, stream>>>(d_in[9], d_in[15], bgc, flag);

  // fused convert + mean-partials + K/V projection (graph produces partials)
  proj_kv_fused<<<dim3(BB * GLEN / 64), dim3(512), 0, stream>>>(
      graph, WT[6], WT[7], Kg, Vgt, GLEN, partG, flag);
  proj_kv_fused<<<dim3(BB * PLEN / 64), dim3(512), 0, stream>>>(
      pattern, WT[1], WT[2], Kp, Vpt, PLEN, (float*)nullptr, flag);
  finalize_q0<<<dim3(BB * ML), dim3(256), 0, stream>>>(partG, d_in[4], memf, hq, flag);

  for (int s = 0; s < 3; s++) {
    // pattern attention
    flash_partial<<<dim3(8, BB), dim3(256), 0, stream>>>(hq, Kp, Vpt, pmask, pm, pl, pO, PLEN, 8);
    epilogue<<<dim3(BB), dim3(256), 0, stream>>>(pm, pl, pO, 8, memf, WT[3], WT[4], bgc,
                                                 (const short*)WT[5], hq, (void*)nullptr, flag);
    // graph attention
    bool last = (s == 2);
    flash_partial<<<dim3(32, BB), dim3(256), 0, stream>>>(hq, Kg, Vgt, gmask, pm, pl, pO, GLEN, 32);
    epilogue<<<dim3(BB), dim3(256), 0, stream>>>(pm, pl, pO, 32, memf, WT[8], WT[9], bgc + 256,
                                                 last ? (const short*)nullptr : (const short*)WT[0],
                                                 hq, last ? d_out : (void*)nullptr, flag);
  }
}